// Round 8
// baseline (108.183 us; speedup 1.0000x reference)
//
#include <hip/hip_runtime.h>

#define NPTS 1024
#define NA   60
#define CIN  64
#define KSZ  3
#define ANN  8
#define COUT 128
#define KD   192   // i' = k_s*64 + c, 6 k-tiles of 32

using bf16x8 = __attribute__((ext_vector_type(8))) short;
using f32x4  = __attribute__((ext_vector_type(4))) float;

__device__ __forceinline__ unsigned short f2bf(float f) {
    unsigned int u = __builtin_bit_cast(unsigned int, f);
    u += 0x7FFFu + ((u >> 16) & 1u);          // RNE
    return (unsigned short)(u >> 16);
}

// async 16B global->LDS DMA (zero VGPR cost per outstanding load)
__device__ __forceinline__ void gload_lds16(const float* g, void* l) {
    __builtin_amdgcn_global_load_lds(
        (const __attribute__((address_space(1))) unsigned int*)g,
        (__attribute__((address_space(3))) unsigned int*)l,
        16, 0, 0);
}

// d_ws layout (shorts):
//   [0      .. 24576)  W_frag[mt=8][kt=6][lane=64][j=8]   (A-frag layout)
//   [24576  .. 36864)  S_frag[nt=12][kt=2][lane=64][j=8]  (B-frag layout)
__global__ void build_tables(const float* __restrict__ intra_w,
                             const float* __restrict__ W,
                             const int*   __restrict__ intra_idx,
                             unsigned short* __restrict__ ws) {
    int f = blockIdx.x * 256 + threadIdx.x;
    if (f < 24576) {
        int j = f & 7, l = (f >> 3) & 63, x = f >> 9;
        int kt = x % 6, mt = x / 6;
        int m  = mt * 16 + (l & 15);
        int ip = kt * 32 + 8 * (l >> 4) + j;      // i'
        int c  = ip & 63, ks = ip >> 6;
        ws[f] = f2bf(W[m * KD + c * KSZ + ks]);
    } else if (f < 36864) {
        int f2 = f - 24576;
        int j = f2 & 7, l = (f2 >> 3) & 63;
        int kt = (f2 >> 9) & 1, nt = f2 >> 10;
        int np = nt * 16 + (l & 15);              // n' = ks*60+o
        int ap = kt * 32 + 8 * (l >> 4) + j;      // a'
        float s = 0.f;
        if (np < 180 && ap < 60) {
            int ks = (np >= 120) ? 2 : ((np >= 60) ? 1 : 0);
            int o  = np - 60 * ks;
            const int*   ix = intra_idx + (o * KSZ + ks) * ANN;
            const float* wx = intra_w   + (o * KSZ + ks) * ANN;
            #pragma unroll
            for (int a = 0; a < ANN; a++) s += (ix[a] == ap) ? wx[a] : 0.f;
        }
        ws[f] = f2bf(s);
    }
}

// ---------------- persistent kernel: 256 blocks (1/CU), 512 threads, 8 points each ----------------
// Proven round-7 sync template: stage -> bar -> { G1 -> bar -> G2 -> bar } x8.
// NEW: feats staged raw-f32 via global_load_lds DMA (latency-proof), cvt moved into G1 frag build.
__global__ __launch_bounds__(512, 2)
void intrazp_persist(const float* __restrict__ feats,
                     const float* __restrict__ bias,
                     const unsigned short* __restrict__ ws,
                     float* __restrict__ out) {
    // fsF[pt=8][c=64][a=60] f32, LINEAR (DMA-written). 122880 B.
    // AsT[o=64][i'=192] bf16, swizzled: byte = (o*384 + i'*2) ^ ((o&7)<<4). 24576 B.
    __shared__ __align__(16) float fsF[8 * 64 * 60];
    __shared__ __align__(16) unsigned short AsT[64 * 192];

    const int t    = threadIdx.x;
    const int wave = t >> 6, lane = t & 63;
    const int l15  = lane & 15, g = lane >> 4;
    const int x    = blockIdx.x;                 // 256 blocks
    const int b    = x >> 7, pbase = (x & 127) * 8;

    // ---- role split ----
    const int wm  = wave & 1, wn = wave >> 1;    // GEMM-1: mtile-pair, ntile-triple
    const int h   = wave >> 2, nt2 = wave & 3;   // GEMM-2: mtile-quad half, ntile

    // ---- stage ALL 8 points' feats via async DMA: wave w stages pt=w ----
    // slot s = w*960 + r*64 + lane (16B units); [pt][c][15 slots of 16B]
    {
        const float* fb = feats + (size_t)b * CIN * NPTS * NA + (size_t)pbase * NA;
        #pragma unroll
        for (int r = 0; r < 15; r++) {
            int rem = r * 64 + lane;              // 0..959
            int c = rem / 15, w = rem - c * 15;
            const float* gp = fb + (size_t)c * (NPTS * NA) + wave * NA + w * 4;
            gload_lds16(gp, (char*)fsF + wave * 15360 + r * 1024);
        }
        if (t < 192) {  // zero-pad AsT rows o=60..63 (G1 never writes them)
            *(uint2*)((char*)AsT + 60 * 384 + t * 8) = make_uint2(0u, 0u);
        }
    }

    // ---- hoist constants (loaded ONCE per block, reused for 8 points);
    //      their latency overlaps the DMA drain ----
    const unsigned short* Sfrag = ws + 24576;
    bf16x8 Sreg[3][2];
    #pragma unroll
    for (int ni = 0; ni < 3; ni++)
        #pragma unroll
        for (int kt = 0; kt < 2; kt++)
            Sreg[ni][kt] = *(const bf16x8*)(Sfrag + (((3 * wn + ni) * 2 + kt) * 64 + lane) * 8);

    bf16x8 Wreg[4][6];
    #pragma unroll
    for (int m = 0; m < 4; m++)
        #pragma unroll
        for (int kt = 0; kt < 6; kt++)
            Wreg[m][kt] = *(const bf16x8*)(ws + (((h * 4 + m) * 6 + kt) * 64 + lane) * 8);

    float4 bvv[4];
    #pragma unroll
    for (int m = 0; m < 4; m++)
        bvv[m] = *(const float4*)(bias + (h * 4 + m) * 16 + 4 * g);

    __syncthreads();   // __syncthreads drains vmcnt(0): all DMAs landed

    // ---- per-point: G1 -> barrier -> G2 -> barrier ----
    for (int pt = 0; pt < 8; ++pt) {
        // GEMM-1: G[c][(ks,o)] = fs_pt(64x60) * S(60x180)
        bf16x8 a1[2][2];
        #pragma unroll
        for (int mi = 0; mi < 2; mi++) {
            int c = (wm * 2 + mi) * 16 + l15;
            const float* fsrow = fsF + pt * 3840 + c * 60;
            #pragma unroll
            for (int kt = 0; kt < 2; kt++) {
                int a0 = kt * 32 + 8 * g;                 // <= 56
                float4 lo = *(const float4*)(fsrow + a0);
                int ah = a0 + 4;
                bool pad = (ah >= NA);                    // only kt==1, g==3
                float4 hi = *(const float4*)(fsrow + (pad ? a0 : ah));
                bf16x8 v;
                v[0] = (short)f2bf(lo.x); v[1] = (short)f2bf(lo.y);
                v[2] = (short)f2bf(lo.z); v[3] = (short)f2bf(lo.w);
                v[4] = (short)(pad ? 0 : f2bf(hi.x));
                v[5] = (short)(pad ? 0 : f2bf(hi.y));
                v[6] = (short)(pad ? 0 : f2bf(hi.z));
                v[7] = (short)(pad ? 0 : f2bf(hi.w));
                a1[mi][kt] = v;
            }
        }
        #pragma unroll
        for (int ni = 0; ni < 3; ni++) {
            int nt = 3 * wn + ni;
            int np = nt * 16 + l15;               // n' = ks*60 + o
            int ks = (np >= 120) ? 2 : ((np >= 60) ? 1 : 0);
            int o  = np - 60 * ks;
            int sw = (o & 7) << 4;
            int rowbyte = o * 384;
            #pragma unroll
            for (int mi = 0; mi < 2; mi++) {
                f32x4 acc1 = {0.f, 0.f, 0.f, 0.f};
                acc1 = __builtin_amdgcn_mfma_f32_16x16x32_bf16(a1[mi][0], Sreg[ni][0], acc1, 0, 0, 0);
                acc1 = __builtin_amdgcn_mfma_f32_16x16x32_bf16(a1[mi][1], Sreg[ni][1], acc1, 0, 0, 0);
                if (np < 180) {
                    int cbase = (wm * 2 + mi) * 16 + 4 * g;
                    int ipb   = ks * 64 + cbase;   // i' rows consecutive (cbase mult of 4)
                    unsigned int lo = (unsigned int)f2bf(acc1[0]) | ((unsigned int)f2bf(acc1[1]) << 16);
                    unsigned int hi = (unsigned int)f2bf(acc1[2]) | ((unsigned int)f2bf(acc1[3]) << 16);
                    int byte = (rowbyte + ipb * 2) ^ sw;
                    *(uint2*)((char*)AsT + byte) = make_uint2(lo, hi);
                }
            }
        }

        __syncthreads();   // AsT complete before any G2 read

        // GEMM-2: out[co][o] = W(128x192) * As(192x60) + bias
        int o   = nt2 * 16 + l15;
        int swo = (o & 7) << 4, rbo = o * 384;
        bf16x8 bb[6];
        #pragma unroll
        for (int kt = 0; kt < 6; kt++)
            bb[kt] = *(const bf16x8*)((char*)AsT + ((rbo + (kt * 32 + 8 * g) * 2) ^ swo));

        f32x4 acc[4];
        #pragma unroll
        for (int m = 0; m < 4; m++) acc[m] = (f32x4){0.f, 0.f, 0.f, 0.f};
        #pragma unroll
        for (int kt = 0; kt < 6; kt++)
            #pragma unroll
            for (int m = 0; m < 4; m++)
                acc[m] = __builtin_amdgcn_mfma_f32_16x16x32_bf16(Wreg[m][kt], bb[kt], acc[m], 0, 0, 0);

        // epilogue
        int p = pbase + pt;
        if (o < NA) {
            const size_t cs = (size_t)NPTS * NA;
            #pragma unroll
            for (int m = 0; m < 4; m++) {
                int cbase = (h * 4 + m) * 16 + 4 * g;
                float* ob = out + (((size_t)b * COUT + cbase) * NPTS + p) * NA + o;
                ob[0 * cs] = acc[m][0] + bvv[m].x;
                ob[1 * cs] = acc[m][1] + bvv[m].y;
                ob[2 * cs] = acc[m][2] + bvv[m].z;
                ob[3 * cs] = acc[m][3] + bvv[m].w;
            }
        }

        __syncthreads();   // all G2 reads done before next G1 overwrites AsT
    }
}

extern "C" void kernel_launch(void* const* d_in, const int* in_sizes, int n_in,
                              void* d_out, int out_size, void* d_ws, size_t ws_size,
                              hipStream_t stream) {
    const float* feats     = (const float*)d_in[0];
    const float* intra_w   = (const float*)d_in[1];
    const float* W         = (const float*)d_in[2];
    const float* bias      = (const float*)d_in[3];
    const int*   intra_idx = (const int*)d_in[4];
    float* out = (float*)d_out;
    unsigned short* ws = (unsigned short*)d_ws;   // needs 73728 B

    build_tables<<<dim3(144), dim3(256), 0, stream>>>(intra_w, W, intra_idx, ws);
    intrazp_persist<<<dim3(256), dim3(512), 0, stream>>>(feats, bias, ws, out);
}

// Round 9
// 106.498 us; speedup vs baseline: 1.0158x; 1.0158x over previous
//
#include <hip/hip_runtime.h>

#define NPTS 1024
#define NA   60
#define CIN  64
#define KSZ  3
#define ANN  8
#define COUT 128
#define KD   192   // i' = k_s*64 + c, 6 k-tiles of 32

using bf16x8 = __attribute__((ext_vector_type(8))) short;
using f32x4  = __attribute__((ext_vector_type(4))) float;

__device__ __forceinline__ unsigned short f2bf(float f) {
    unsigned int u = __builtin_bit_cast(unsigned int, f);
    u += 0x7FFFu + ((u >> 16) & 1u);          // RNE
    return (unsigned short)(u >> 16);
}

// d_ws layout (shorts):
//   [0      .. 24576)  W_frag[mt=8][kt=6][lane=64][j=8]   (A-frag layout)
//   [24576  .. 36864)  S_frag[nt=12][kt=2][lane=64][j=8]  (B-frag layout)
__global__ void build_tables(const float* __restrict__ intra_w,
                             const float* __restrict__ W,
                             const int*   __restrict__ intra_idx,
                             unsigned short* __restrict__ ws) {
    int f = blockIdx.x * 256 + threadIdx.x;
    if (f < 24576) {
        int j = f & 7, l = (f >> 3) & 63, x = f >> 9;
        int kt = x % 6, mt = x / 6;
        int m  = mt * 16 + (l & 15);
        int ip = kt * 32 + 8 * (l >> 4) + j;      // i'
        int c  = ip & 63, ks = ip >> 6;
        ws[f] = f2bf(W[m * KD + c * KSZ + ks]);
    } else if (f < 36864) {
        int f2 = f - 24576;
        int j = f2 & 7, l = (f2 >> 3) & 63;
        int kt = (f2 >> 9) & 1, nt = f2 >> 10;
        int np = nt * 16 + (l & 15);              // n' = ks*60+o
        int ap = kt * 32 + 8 * (l >> 4) + j;      // a'
        float s = 0.f;
        if (np < 180 && ap < 60) {
            int ks = (np >= 120) ? 2 : ((np >= 60) ? 1 : 0);
            int o  = np - 60 * ks;
            const int*   ix = intra_idx + (o * KSZ + ks) * ANN;
            const float* wx = intra_w   + (o * KSZ + ks) * ANN;
            #pragma unroll
            for (int a = 0; a < ANN; a++) s += (ix[a] == ap) ? wx[a] : 0.f;
        }
        ws[f] = f2bf(s);
    }
}

// ---------------- main kernel: 512 blocks (2/CU), 256 threads (4 waves), 4 points each ----------------
// Proven r7 sync template: stage -> bar -> { G1 -> bar -> G2 -> bar } x4.
// Proven r7 swizzled-bf16 staging. Proven r4 4-wave role mapping. 56 KB LDS -> 2 blocks/CU.
__global__ __launch_bounds__(256, 2)
void intrazp_persist(const float* __restrict__ feats,
                     const float* __restrict__ bias,
                     const unsigned short* __restrict__ ws,
                     float* __restrict__ out) {
    // fsS2[c=64][pt=4][a=64] bf16, swizzled: byte = (c*512 + pt*128 + a*2) ^ ((c&7)<<4)
    // AsT[o=64][i'=192] bf16, swizzled: byte = (o*384 + i'*2) ^ ((o&7)<<4)
    __shared__ __align__(16) unsigned short fsS2[64 * 4 * 64];     // 32 KB
    __shared__ __align__(16) unsigned short AsT[64 * 192];         // 24 KB

    const int t    = threadIdx.x;
    const int wave = t >> 6, lane = t & 63;
    const int l15  = lane & 15, g = lane >> 4;
    const int x    = blockIdx.x;                 // 512 blocks
    const int b    = x >> 8, pbase = (x & 255) * 4;

    // ---- role split (round-4 proven 4-wave mapping) ----
    const int wm = wave & 1, wn = wave >> 1;     // G1: mtile-pair, ntile-sextet

    // ---- hoist constants (loaded ONCE per block, reused for 4 points) ----
    const unsigned short* Sfrag = ws + 24576;
    bf16x8 Sreg[6][2];
    #pragma unroll
    for (int ni = 0; ni < 6; ni++)
        #pragma unroll
        for (int kt = 0; kt < 2; kt++)
            Sreg[ni][kt] = *(const bf16x8*)(Sfrag + (((wn * 6 + ni) * 2 + kt) * 64 + lane) * 8);

    bf16x8 Wreg[2][6];                           // G2: wave owns mtiles {2w, 2w+1}
    #pragma unroll
    for (int mi = 0; mi < 2; mi++)
        #pragma unroll
        for (int kt = 0; kt < 6; kt++)
            Wreg[mi][kt] = *(const bf16x8*)(ws + (((wave * 2 + mi) * 6 + kt) * 64 + lane) * 8);

    float4 bvv[2];
    #pragma unroll
    for (int mi = 0; mi < 2; mi++)
        bvv[mi] = *(const float4*)(bias + (wave * 2 + mi) * 16 + 4 * g);

    // ---- stage 4 points' feats (coalesced float4, bf16 cvt, swizzled LDS) ----
    {
        const float* fb = feats + (size_t)b * CIN * NPTS * NA + (size_t)pbase * NA;
        #pragma unroll
        for (int r = 0; r < 15; r++) {
            int gid = r * 256 + t;               // 0..3839 (15 float4 per (c,pt) row)
            int c  = gid / 60, u = gid - c * 60;
            int pt = u / 15,   w = u - pt * 15;
            float4 v = *(const float4*)(fb + (size_t)c * NPTS * NA + pt * NA + w * 4);
            unsigned int lo = (unsigned int)f2bf(v.x) | ((unsigned int)f2bf(v.y) << 16);
            unsigned int hi = (unsigned int)f2bf(v.z) | ((unsigned int)f2bf(v.w) << 16);
            int byte = (c * 512 + pt * 128 + w * 8) ^ ((c & 7) << 4);
            *(uint2*)((char*)fsS2 + byte) = make_uint2(lo, hi);
        }
        {   // zero-pad a = 60..63 for every (c, pt): 256 slots
            int c = t >> 2, pt = t & 3;
            int byte = (c * 512 + pt * 128 + 120) ^ ((c & 7) << 4);
            *(uint2*)((char*)fsS2 + byte) = make_uint2(0u, 0u);
        }
        if (t < 192) {  // zero-pad AsT rows o=60..63 (G1 never writes them)
            *(uint2*)((char*)AsT + 60 * 384 + t * 8) = make_uint2(0u, 0u);
        }
    }
    __syncthreads();

    // ---- per-point: G1 -> barrier -> G2 -> barrier ----
    for (int pt = 0; pt < 4; ++pt) {
        // GEMM-1: G[c][(ks,o)] = fs_pt(64x60) * S(60x180)
        bf16x8 a1[2][2];
        #pragma unroll
        for (int mi = 0; mi < 2; mi++) {
            int c = (wm * 2 + mi) * 16 + l15;
            #pragma unroll
            for (int kt = 0; kt < 2; kt++) {
                int byte = (c * 512 + pt * 128 + kt * 64 + g * 16) ^ ((c & 7) << 4);
                a1[mi][kt] = *(const bf16x8*)((char*)fsS2 + byte);
            }
        }
        #pragma unroll
        for (int ni = 0; ni < 6; ni++) {
            int nt = wn * 6 + ni;
            int np = nt * 16 + l15;               // n' = ks*60 + o
            int ks = (np >= 120) ? 2 : ((np >= 60) ? 1 : 0);
            int o  = np - 60 * ks;
            int sw = (o & 7) << 4;
            int rowbyte = o * 384;
            #pragma unroll
            for (int mi = 0; mi < 2; mi++) {
                f32x4 acc1 = {0.f, 0.f, 0.f, 0.f};
                acc1 = __builtin_amdgcn_mfma_f32_16x16x32_bf16(a1[mi][0], Sreg[ni][0], acc1, 0, 0, 0);
                acc1 = __builtin_amdgcn_mfma_f32_16x16x32_bf16(a1[mi][1], Sreg[ni][1], acc1, 0, 0, 0);
                if (np < 180) {
                    int cbase = (wm * 2 + mi) * 16 + 4 * g;
                    int ipb   = ks * 64 + cbase;   // i' rows consecutive (cbase mult of 4)
                    unsigned int lo = (unsigned int)f2bf(acc1[0]) | ((unsigned int)f2bf(acc1[1]) << 16);
                    unsigned int hi = (unsigned int)f2bf(acc1[2]) | ((unsigned int)f2bf(acc1[3]) << 16);
                    int byte = (rowbyte + ipb * 2) ^ sw;
                    *(uint2*)((char*)AsT + byte) = make_uint2(lo, hi);
                }
            }
        }

        __syncthreads();   // AsT complete before any G2 read

        // GEMM-2: out[co][o] = W(128x192) * As(192x60) + bias  (round-4 proven code)
        int rb[4], swz[4], ov[4];
        #pragma unroll
        for (int nt = 0; nt < 4; nt++) {
            int o = nt * 16 + l15;
            ov[nt]  = o;
            rb[nt]  = o * 384;
            swz[nt] = (o & 7) << 4;
        }

        f32x4 acc[2][4];
        #pragma unroll
        for (int mi = 0; mi < 2; mi++)
            #pragma unroll
            for (int nt = 0; nt < 4; nt++) acc[mi][nt] = (f32x4){0.f, 0.f, 0.f, 0.f};

        #pragma unroll
        for (int kt = 0; kt < 6; kt++) {
            int x2 = (kt * 32 + 8 * g) * 2;
            bf16x8 bb[4];
            #pragma unroll
            for (int nt = 0; nt < 4; nt++)
                bb[nt] = *(const bf16x8*)((char*)AsT + ((rb[nt] + x2) ^ swz[nt]));
            #pragma unroll
            for (int mi = 0; mi < 2; mi++)
                #pragma unroll
                for (int nt = 0; nt < 4; nt++)
                    acc[mi][nt] = __builtin_amdgcn_mfma_f32_16x16x32_bf16(Wreg[mi][kt], bb[nt], acc[mi][nt], 0, 0, 0);
        }

        // epilogue
        int p = pbase + pt;
        #pragma unroll
        for (int mi = 0; mi < 2; mi++) {
            int cbase = (wave * 2 + mi) * 16 + 4 * g;
            float* ob = out + (((size_t)b * COUT + cbase) * NPTS + p) * NA;
            const size_t cs = (size_t)NPTS * NA;
            #pragma unroll
            for (int nt = 0; nt < 4; nt++) {
                if (ov[nt] < NA) {
                    ob[0 * cs + ov[nt]] = acc[mi][nt][0] + bvv[mi].x;
                    ob[1 * cs + ov[nt]] = acc[mi][nt][1] + bvv[mi].y;
                    ob[2 * cs + ov[nt]] = acc[mi][nt][2] + bvv[mi].z;
                    ob[3 * cs + ov[nt]] = acc[mi][nt][3] + bvv[mi].w;
                }
            }
        }

        __syncthreads();   // all G2 reads done before next G1 overwrites AsT
    }
}

extern "C" void kernel_launch(void* const* d_in, const int* in_sizes, int n_in,
                              void* d_out, int out_size, void* d_ws, size_t ws_size,
                              hipStream_t stream) {
    const float* feats     = (const float*)d_in[0];
    const float* intra_w   = (const float*)d_in[1];
    const float* W         = (const float*)d_in[2];
    const float* bias      = (const float*)d_in[3];
    const int*   intra_idx = (const int*)d_in[4];
    float* out = (float*)d_out;
    unsigned short* ws = (unsigned short*)d_ws;   // needs 73728 B

    build_tables<<<dim3(144), dim3(256), 0, stream>>>(intra_w, W, intra_idx, ws);
    intrazp_persist<<<dim3(512), dim3(256), 0, stream>>>(feats, bias, ws, out);
}